// Round 15
// baseline (235.836 us; speedup 1.0000x reference)
//
#include <hip/hip_runtime.h>
#include <math.h>

// ---------------------------------------------------------------------------
// GaussianQuant — MFMA-filtered argmax, R25.
// score[n,k] = sum_d p*c + q*c^2;  u=[p,q], v=[c,c^2], score = u.v  (K=64)
// fp16 HI-ONLY approx, rigorous per-k error:
//   err_k <= 1.05e-3 * (||p||2*||c_k||2 + ||q||2*||c_k^2||2)   (Cauchy-Schwarz)
// R24 post-mortem: cbP (contiguous rescans) = null -> merge's 25us is not
// traffic. R18 (bound) null, R23 (restructure) regressed. Remaining theory:
// LATENCY — each block-round's chained phases (~2.5-3k cyc) predict ~6us at
// 4 blocks/CU x 4 rounds; measured 25us => chains not overlapping. R25:
// each wave processes 2 ROWS (block = 8 rows, grid = 2048) as independent
// interleaved straight-line chains: both seed scans' 16 float4 loads issue
// together; chain B's W1 loads share chain A's cache lines (rows r,r+1 are
// 32B apart in [split][row][16]). In-flight chains/CU double, zero extra
// traffic. VGPR ~110 < 128 cap (launch_bounds(256,4)) -> occupancy holds.
// prep + filter + cbP = R24c VERBATIM.
// ---------------------------------------------------------------------------

typedef _Float16 half8 __attribute__((ext_vector_type(8)));
typedef float f32x4 __attribute__((ext_vector_type(4)));

#define DIM 32
#define NROWS 16384
#define KSIZE 16384
#define NSPLIT 16
#define SPLITK 1024
#define NCOL 256

// ws layout (bytes); [0,4096) zeroed by memset each launch
#define WS_M1   0                       // (unused, kept for layout stability)
#define WS_KL   256                     // 1 double (atomicAdd target)
#define WS_CN1  512                     // 256 float (atomicMax: max ||c_k||)
#define WS_CN2  1536                    // 256 float (atomicMax: max ||c_k^2||)
#define WS_PQ   4096                    // 4 MB fp32 [row][64]
#define WS_AH   (WS_PQ + 4194304)       // 2 MB fp16 [row][64]
#define WS_BH   (WS_AH + 2097152)       // 2 MB fp16 [k][64] PRE-SWIZZLED
#define WS_W1   (WS_BH + 2097152)       // 8 MB fp16 [split][row][16]
#define WS_CBP  (WS_W1 + 8388608)       // 2 MB fp32 [col][64][32] column-major

// Fused prep, 1024 blocks (R24c verbatim):
// [0,512): codebook pack (swizzled Bh, 16-B stores) + column-major cbP +
//          per-column norm maxima.
// [512,1024): p,q + fp16 pack + KL partial. Each wave: 1 token, coalesced.
__global__ __launch_bounds__(256) void prep_kernel(const float* __restrict__ cb,
                                                   const float* __restrict__ z,
                                                   _Float16* __restrict__ Bh,
                                                   float* __restrict__ cbP,
                                                   float* __restrict__ CN1,
                                                   float* __restrict__ CN2,
                                                   float* __restrict__ PQ,
                                                   _Float16* __restrict__ Ah,
                                                   double* __restrict__ klsum) {
  const int w = threadIdx.x >> 6, l = threadIdx.x & 63;
  if (blockIdx.x < 512) {
    // ---- codebook half: 32 k's per block (8 per wave) ----
    const int k = blockIdx.x * 32 + w * 8 + (l >> 3);
    const int s_phys = l & 7;
    const int logical = s_phys ^ (k & 7);
    const int base = (logical & 3) * 8;            // dim group start
    const float4 cA = *(const float4*)(cb + k * DIM + base);
    const float4 cB = *(const float4*)(cb + k * DIM + base + 4);
    float v[8] = {cA.x, cA.y, cA.z, cA.w, cB.x, cB.y, cB.z, cB.w};

    half8 hv;
    if (logical < 4) {
#pragma unroll
      for (int i = 0; i < 8; ++i) hv[i] = (_Float16)v[i];
    } else {
#pragma unroll
      for (int i = 0; i < 8; ++i) hv[i] = (_Float16)(v[i] * v[i]);
    }
    *(half8*)(Bh + (size_t)k * 64 + s_phys * 8) = hv;   // 16-B store, coalesced

    // column-major copy for merge rescans: lanes logical<4 cover dims 0..31
    const int col = (k >> 10) * 16 + (k & 15);
    const int j = (k >> 4) & 63;
    if (logical < 4) {
      float* dst = cbP + ((size_t)col * 64 + j) * 32 + base;
      *(float4*)dst = cA;
      *(float4*)(dst + 4) = cB;
    }

    // per-k norms: lanes with logical<4 cover dims 0..31 exactly once
    float s2 = 0.0f, s4 = 0.0f;
    if (logical < 4) {
#pragma unroll
      for (int i = 0; i < 8; ++i) {
        const float c2 = v[i] * v[i];
        s2 += c2;
        s4 += c2 * c2;
      }
    }
#pragma unroll
    for (int mask = 1; mask <= 4; mask <<= 1) {     // 8-lane group reduce
      s2 += __shfl_xor(s2, mask);
      s4 += __shfl_xor(s4, mask);
    }
    if (s_phys == 0) {
      atomicMax((unsigned*)&CN1[col], __float_as_uint(sqrtf(s2)));
      atomicMax((unsigned*)&CN2[col], __float_as_uint(sqrtf(s4)));
    }
  } else {
    // ---- z half: 4 tokens per block (1 per wave), fully coalesced ----
    const int tok = (blockIdx.x - 512) * 4 + w;
    const float4 mu4 = ((const float4*)z)[(size_t)tok * 128 + l];        // mu
    const float4 lv4 = ((const float4*)z)[(size_t)tok * 128 + 64 + l];   // logvar
    const int d = l >> 1;
    const int c0 = (l & 1) * 4;
    double kacc = 0.0;
#pragma unroll
    for (int e = 0; e < 4; ++e) {
      const float mu = ((const float*)&mu4)[e];
      float lv = ((const float*)&lv4)[e];
      lv = fminf(fmaxf(lv, -30.0f), 20.0f);
      const float stdv = expf(0.5f * lv);
      const float iv = 1.0f / (stdv * stdv);   // identical to R2 expression
      const float p = mu * iv;
      const float q = 0.5f * (1.0f - iv);
      const size_t row = (size_t)tok * 8 + c0 + e;
      PQ[row * 64 + d] = p;                    // contiguous across lanes
      PQ[row * 64 + 32 + d] = q;
      Ah[row * 64 + d] = (_Float16)p;
      Ah[row * 64 + 32 + d] = (_Float16)q;
      kacc += (double)(mu * mu + stdv * stdv - 1.0f - lv);
    }
#pragma unroll
    for (int off = 32; off > 0; off >>= 1) kacc += __shfl_down(kacc, off);
    __shared__ double wsum[4];
    if (l == 0) wsum[w] = kacc;
    __syncthreads();
    if (threadIdx.x == 0)
      atomicAdd(klsum, (wsum[0] + wsum[1]) + (wsum[2] + wsum[3]));
  }
}

// async global->LDS, 16B per lane; dest must be linear in lane order.
__device__ __forceinline__ void gload_lds16(const _Float16* g, _Float16* l) {
  __builtin_amdgcn_global_load_lds(
      (__attribute__((address_space(1))) void*)(g),
      (__attribute__((address_space(3))) void*)(l), 16, 0, 0);
}

// grid (32, 16): x = rowgroup (512 rows), y = split. 4 waves x 128 rows each
// (8 rowtiles, A resident = 64 VGPR). B staged through 2 x 32 KB LDS buffers
// (16 tiles/chunk) via global_load_lds; 4 chunks, 1 barrier each. (R19/R22)
__global__ __launch_bounds__(256, 2) void filter_kernel(const _Float16* __restrict__ Ah,
                                                        const _Float16* __restrict__ Bh,
                                                        _Float16* __restrict__ W1) {
  __shared__ _Float16 sB[2][16384];   // 2 x 32 KB
  const int tid = threadIdx.x;
  const int lane = tid & 63;
  const int wave = tid >> 6;
  const int split = blockIdx.y;
  const int rowbase = blockIdx.x * 512 + wave * 128;   // 8 rowtiles of 16
  const int c16 = lane & 15, quad = lane >> 4;

  const _Float16* gB = Bh + (size_t)split * SPLITK * 64;  // 128 KB region

  // async-stage chunk 0 -> buf 0 (linear copy: Bh pre-swizzled in prep)
#pragma unroll
  for (int j = 0; j < 8; ++j)
    gload_lds16(gB + j * 2048 + tid * 8, &sB[0][j * 2048 + tid * 8]);

  half8 uh0[8], uh1[8];
#pragma unroll
  for (int rt = 0; rt < 8; ++rt) {
    const size_t abase = (size_t)(rowbase + rt * 16 + c16) * 64 + quad * 8;
    uh0[rt] = *(const half8*)(Ah + abase);
    uh1[rt] = *(const half8*)(Ah + abase + 32);
  }

  float a1[8][4];
#pragma unroll
  for (int rt = 0; rt < 8; ++rt)
#pragma unroll
    for (int r = 0; r < 4; ++r) a1[rt][r] = -INFINITY;

  const f32x4 fzero = {0.f, 0.f, 0.f, 0.f};
  // swizzled read offsets (halfs): row c16, physical slot = logical ^ (c16&7)
  const int key = c16 & 7;
  const int rs0h = c16 * 64 + (quad ^ key) * 8;         // p-part (slots 0-3)
  const int rs1h = c16 * 64 + ((quad + 4) ^ key) * 8;   // q-part (slots 4-7)

  __syncthreads();   // chunk 0 landed (compiler drains vmcnt before barrier)

#pragma unroll 1
  for (int ch = 0; ch < 4; ++ch) {
    if (ch < 3) {    // issue next chunk into the idle buffer (async)
      const _Float16* src = gB + (size_t)(ch + 1) * 16384;
      _Float16* dst = &sB[(ch + 1) & 1][0];
#pragma unroll
      for (int j = 0; j < 8; ++j)
        gload_lds16(src + j * 2048 + tid * 8, dst + j * 2048 + tid * 8);
    }
    const _Float16* buf = &sB[ch & 1][0];
#pragma unroll 1
    for (int tp = 0; tp < 8; ++tp) {          // 8 tile-pairs per chunk
      const _Float16* b0 = buf + (2 * tp) * 1024;
      const _Float16* b1 = b0 + 1024;
      const half8 x0 = *(const half8*)(b0 + rs0h);
      const half8 x1 = *(const half8*)(b0 + rs1h);
      const half8 y0 = *(const half8*)(b1 + rs0h);
      const half8 y1 = *(const half8*)(b1 + rs1h);
#pragma unroll
      for (int rt = 0; rt < 8; ++rt) {
        f32x4 h0 = __builtin_amdgcn_mfma_f32_16x16x32_f16(uh0[rt], x0, fzero, 0, 0, 0);
        h0 = __builtin_amdgcn_mfma_f32_16x16x32_f16(uh1[rt], x1, h0, 0, 0, 0);
        f32x4 h1 = __builtin_amdgcn_mfma_f32_16x16x32_f16(uh0[rt], y0, fzero, 0, 0, 0);
        h1 = __builtin_amdgcn_mfma_f32_16x16x32_f16(uh1[rt], y1, h1, 0, 0, 0);
#pragma unroll
        for (int r = 0; r < 4; ++r)
          a1[rt][r] = fmaxf(fmaxf(h0[r], h1[r]), a1[rt][r]);   // v_max3
      }
    }
    __syncthreads();  // all waves done with buf; next chunk landed (vmcnt 0)
  }

  // W1 fp16 [split][row][16]: block-exclusive contiguous 16KB, no RMW.
#pragma unroll
  for (int rt = 0; rt < 8; ++rt)
#pragma unroll
    for (int r = 0; r < 4; ++r) {
      const int row_r = rowbase + rt * 16 + quad * 4 + r;   // C: row=quad*4+r
      W1[((size_t)split * NROWS + row_r) * 16 + c16] =
          (_Float16)fmaxf(a1[rt][r], -65504.0f);
    }
}

// exact fp32 score from the COLUMN-MAJOR copy: column col, slot j (=lane).
// 8 KB contiguous per column scan; identical float expression to R2.
__device__ __forceinline__ float exact_score_cm(const float4* __restrict__ cbP4,
                                                const float4* __restrict__ spq,
                                                int col, int j) {
  const float4* cp = cbP4 + ((size_t)col * 64 + j) * 8;
  float s0 = 0.0f, s1 = 0.0f, s2 = 0.0f, s3 = 0.0f;
#pragma unroll
  for (int m = 0; m < 8; ++m) {
    const float4 cv = cp[m];
    const float4 pv = spq[m];        // p[4m..4m+3]
    const float4 qv = spq[8 + m];    // q[4m..4m+3]
    s0 = fmaf(cv.x, fmaf(qv.x, cv.x, pv.x), s0);
    s1 = fmaf(cv.y, fmaf(qv.y, cv.y, pv.y), s1);
    s2 = fmaf(cv.z, fmaf(qv.z, cv.z, pv.z), s2);
    s3 = fmaf(cv.w, fmaf(qv.w, cv.w, pv.w), s3);
  }
  return (s0 + s1) + (s2 + s3);
}

// R25 merge: 2 rows per WAVE (block = 8 rows, grid = 2048). Two independent
// interleaved chains per wave double latency hiding; chain B's W1 loads share
// chain A's cache lines. Per-row logic identical to R22/R24.
__global__ __launch_bounds__(256, 4) void merge_kernel(const float* __restrict__ PQ,
                                                       const float* __restrict__ cb,
                                                       const float* __restrict__ cbP,
                                                       const _Float16* __restrict__ W1,
                                                       const float* __restrict__ CN1,
                                                       const float* __restrict__ CN2,
                                                       const double* __restrict__ klsum,
                                                       float* __restrict__ out0,
                                                       float* __restrict__ out1,
                                                       float* __restrict__ out2) {
  __shared__ float4 spq_s[4][2][16];
  const int lane = threadIdx.x & 63;
  const int wave = threadIdx.x >> 6;
  const int rowA = blockIdx.x * 8 + wave * 2;
  const int rowB = rowA + 1;

  if (lane < 16) {
    spq_s[wave][0][lane] = ((const float4*)(PQ + (size_t)rowA * 64))[lane];
    spq_s[wave][1][lane] = ((const float4*)(PQ + (size_t)rowB * 64))[lane];
  }
  __syncthreads();
  const float4* sA = spq_s[wave][0];
  const float4* sB = spq_s[wave][1];
  const float4* __restrict__ cbP4 = (const float4*)cbP;

  // per-row norms ||p||2, ||q||2 (both rows, interleaved shuffle streams)
  float spA = 0.f, sqA = 0.f, spB = 0.f, sqB = 0.f;
  if (lane < DIM) {
    const float pA = ((const float*)sA)[lane], qA = ((const float*)sA)[32 + lane];
    const float pB = ((const float*)sB)[lane], qB = ((const float*)sB)[32 + lane];
    spA = pA * pA; sqA = qA * qA;
    spB = pB * pB; sqB = qB * qB;
  }
#pragma unroll
  for (int off = 1; off < 32; off <<= 1) {
    spA += __shfl_xor(spA, off); sqA += __shfl_xor(sqA, off);
    spB += __shfl_xor(spB, off); sqB += __shfl_xor(sqB, off);
  }
  const float pnA = sqrtf(__shfl(spA, 0)), qnA = sqrtf(__shfl(sqA, 0));
  const float pnB = sqrtf(__shfl(spB, 0)), qnB = sqrtf(__shfl(sqB, 0));

  // 256 column maxima per row; rows A,B are 32B apart -> shared cache lines
  float wA[4], wB[4];
#pragma unroll
  for (int i = 0; i < 4; ++i) {
    const size_t base = ((size_t)(i * 4 + (lane >> 4)) * NROWS);
    wA[i] = (float)W1[(base + rowA) * 16 + (lane & 15)];
    wB[i] = (float)W1[(base + rowB) * 16 + (lane & 15)];
  }
  float AsA = fmaxf(fmaxf(wA[0], wA[1]), fmaxf(wA[2], wA[3]));
  float AsB = fmaxf(fmaxf(wB[0], wB[1]), fmaxf(wB[2], wB[3]));
#pragma unroll
  for (int off = 1; off < 64; off <<= 1) {
    AsA = fmaxf(AsA, __shfl_xor(AsA, off));
    AsB = fmaxf(AsB, __shfl_xor(AsB, off));
  }
  const float slackA = 2e-5f * (fabsf(AsA) + 1.0f) + 1e-3f;
  const float slackB = 2e-5f * (fabsf(AsB) + 1.0f) + 1e-3f;

  float btA[4], btB[4];
#pragma unroll
  for (int i = 0; i < 4; ++i) {
    const int col = i * 64 + lane;
    const float c1 = CN1[col], c2 = CN2[col];
    btA[i] = 1.05e-3f * (pnA * c1 + qnA * c2) + slackA + 5e-4f * fabsf(wA[i]);
    btB[i] = 1.05e-3f * (pnB * c1 + qnB * c2) + slackB + 5e-4f * fabsf(wB[i]);
  }

  // ---- seeds: exact rescan of each row's argmax column (loads overlap) ----
  int dcA = -1, dcB = -1;
#pragma unroll
  for (int i = 0; i < 4; ++i) {
    if (dcA < 0) {
      const unsigned long long m = __ballot(wA[i] == AsA);
      if (m) dcA = i * 64 + __builtin_ctzll(m);
    }
    if (dcB < 0) {
      const unsigned long long m = __ballot(wB[i] == AsB);
      if (m) dcB = i * 64 + __builtin_ctzll(m);
    }
  }
  const int k0A = (dcA >> 4) * SPLITK + lane * 16 + (dcA & 15);
  const int k0B = (dcB >> 4) * SPLITK + lane * 16 + (dcB & 15);
  float bestA = exact_score_cm(cbP4, sA, dcA, lane);   // straight-line:
  float bestB = exact_score_cm(cbP4, sB, dcB, lane);   // 16 float4s in flight
  int bkA = k0A, bkB = k0B;
#pragma unroll
  for (int off = 1; off < 64; off <<= 1) {
    const float ovA = __shfl_xor(bestA, off); const int okA = __shfl_xor(bkA, off);
    if (ovA > bestA || (ovA == bestA && okA < bkA)) { bestA = ovA; bkA = okA; }
    const float ovB = __shfl_xor(bestB, off); const int okB = __shfl_xor(bkB, off);
    if (ovB > bestB || (ovB == bestB && okB < bkB)) { bestB = ovB; bkB = okB; }
  }
  const float EsA = bestA, EsB = bestB;

  // ---- phase B per row: full rescan of surviving columns ----
#pragma unroll 1
  for (int i = 0; i < 4; ++i) {
    unsigned long long mA = __ballot(wA[i] + btA[i] >= EsA);
    if ((dcA >> 6) == i) mA &= ~(1ull << (dcA & 63));
    while (mA) {
      const int e = __builtin_ctzll(mA);
      mA &= mA - 1;
      const int col = i * 64 + e;
      const int k = (col >> 4) * SPLITK + lane * 16 + (col & 15);
      const float sc = exact_score_cm(cbP4, sA, col, lane);
      if (sc > bestA || (sc == bestA && k < bkA)) { bestA = sc; bkA = k; }
    }
    unsigned long long mB = __ballot(wB[i] + btB[i] >= EsB);
    if ((dcB >> 6) == i) mB &= ~(1ull << (dcB & 63));
    while (mB) {
      const int e = __builtin_ctzll(mB);
      mB &= mB - 1;
      const int col = i * 64 + e;
      const int k = (col >> 4) * SPLITK + lane * 16 + (col & 15);
      const float sc = exact_score_cm(cbP4, sB, col, lane);
      if (sc > bestB || (sc == bestB && k < bkB)) { bestB = sc; bkB = k; }
    }
  }
  // final cross-lane argmax, min-k on ties (numpy first-max), both rows
#pragma unroll
  for (int off = 1; off < 64; off <<= 1) {
    const float ovA = __shfl_xor(bestA, off); const int okA = __shfl_xor(bkA, off);
    if (ovA > bestA || (ovA == bestA && okA < bkA)) { bestA = ovA; bkA = okA; }
    const float ovB = __shfl_xor(bestB, off); const int okB = __shfl_xor(bkB, off);
    if (ovB > bestB || (ovB == bestB && okB < bkB)) { bestB = ovB; bkB = okB; }
  }
  if (lane == 0) {
    out2[rowA] = (float)bkA;
    out2[rowB] = (float)bkB;
  }
  const int ttA = rowA >> 3, ccA = rowA & 7;
  const int ttB = rowB >> 3, ccB = rowB & 7;
  if (lane < DIM) {
    out0[ttA * 256 + lane * 8 + ccA] = cb[bkA * DIM + lane];
    out0[ttB * 256 + lane * 8 + ccB] = cb[bkB * DIM + lane];
  }
  if (blockIdx.x == 0 && threadIdx.x == 0)
    out1[0] = (float)(klsum[0] * (1.4426 * 0.5) / (double)NROWS);
}

extern "C" void kernel_launch(void* const* d_in, const int* in_sizes, int n_in,
                              void* d_out, int out_size, void* d_ws, size_t ws_size,
                              hipStream_t stream) {
  const float* z  = (const float*)d_in[0];
  const float* cb = (const float*)d_in[2];   // d_in[1]=noise unused (STE cancels)

  char* ws = (char*)d_ws;
  double* klsum  = (double*)(ws + WS_KL);
  float*     CN1 = (float*)(ws + WS_CN1);
  float*     CN2 = (float*)(ws + WS_CN2);
  float*      PQ = (float*)(ws + WS_PQ);
  _Float16*   Ah = (_Float16*)(ws + WS_AH);
  _Float16*   Bh = (_Float16*)(ws + WS_BH);
  _Float16*   W1 = (_Float16*)(ws + WS_W1);
  float*     cbP = (float*)(ws + WS_CBP);

  float* out0 = (float*)d_out;            // 524288
  float* out1 = out0 + 524288;            // 1
  float* out2 = out1 + 1;                 // 16384

  (void)hipMemsetAsync(ws, 0, 4096, stream);   // klsum, CN1, CN2 = 0
  prep_kernel<<<1024, 256, 0, stream>>>(cb, z, Bh, cbP, CN1, CN2, PQ, Ah, klsum);
  dim3 fgrid(32, NSPLIT);
  filter_kernel<<<fgrid, 256, 0, stream>>>(Ah, Bh, W1);
  merge_kernel<<<NROWS / 8, 256, 0, stream>>>(PQ, cb, cbP, W1, CN1, CN2, klsum,
                                              out0, out1, out2);
}

// Round 16
// 130.197 us; speedup vs baseline: 1.8114x; 1.8114x over previous
//
#include <hip/hip_runtime.h>
#include <math.h>

// ---------------------------------------------------------------------------
// GaussianQuant — MFMA-filtered argmax, R26.
// score[n,k] = sum_d p*c + q*c^2;  u=[p,q], v=[c,c^2], score = u.v  (K=64)
// fp16 HI-ONLY approx, rigorous per-k error:
//   err_k <= 1.05e-3 * (||p||2*||c_k||2 + ||q||2*||c_k^2||2)   (Cauchy-Schwarz)
// R25 post-mortem: 2-row merge showed FETCH 240MB / WRITE 267MB — SCRATCH
// SPILL (rule #20: runtime-indexed arrays -> local memory). Retroactive
// diagnosis: every merge since R14 runtime-indexes w[i]/bt[i] inside a
// "#pragma unroll 1" phase-B loop -> w/bt live in scratch -> ~100MB hidden
// HBM traffic = the unmovable 25us (why cbP/bound/ILP fixes all nulled).
// R26 = R24c VERBATIM except merge phase-B loop is FULLY UNROLLED, making
// all w[i]/bt[i] accesses compile-time-static -> registers, zero scratch.
// ---------------------------------------------------------------------------

typedef _Float16 half8 __attribute__((ext_vector_type(8)));
typedef float f32x4 __attribute__((ext_vector_type(4)));

#define DIM 32
#define NROWS 16384
#define KSIZE 16384
#define NSPLIT 16
#define SPLITK 1024
#define NCOL 256

// ws layout (bytes); [0,4096) zeroed by memset each launch
#define WS_M1   0                       // (unused, kept for layout stability)
#define WS_KL   256                     // 1 double (atomicAdd target)
#define WS_CN1  512                     // 256 float (atomicMax: max ||c_k||)
#define WS_CN2  1536                    // 256 float (atomicMax: max ||c_k^2||)
#define WS_PQ   4096                    // 4 MB fp32 [row][64]
#define WS_AH   (WS_PQ + 4194304)       // 2 MB fp16 [row][64]
#define WS_BH   (WS_AH + 2097152)       // 2 MB fp16 [k][64] PRE-SWIZZLED
#define WS_W1   (WS_BH + 2097152)       // 8 MB fp16 [split][row][16]
#define WS_CBP  (WS_W1 + 8388608)       // 2 MB fp32 [col][64][32] column-major

// Fused prep, 1024 blocks (R24c verbatim):
// [0,512): codebook pack (swizzled Bh, 16-B stores) + column-major cbP +
//          per-column norm maxima.
// [512,1024): p,q + fp16 pack + KL partial. Each wave: 1 token, coalesced.
__global__ __launch_bounds__(256) void prep_kernel(const float* __restrict__ cb,
                                                   const float* __restrict__ z,
                                                   _Float16* __restrict__ Bh,
                                                   float* __restrict__ cbP,
                                                   float* __restrict__ CN1,
                                                   float* __restrict__ CN2,
                                                   float* __restrict__ PQ,
                                                   _Float16* __restrict__ Ah,
                                                   double* __restrict__ klsum) {
  const int w = threadIdx.x >> 6, l = threadIdx.x & 63;
  if (blockIdx.x < 512) {
    // ---- codebook half: 32 k's per block (8 per wave) ----
    const int k = blockIdx.x * 32 + w * 8 + (l >> 3);
    const int s_phys = l & 7;
    const int logical = s_phys ^ (k & 7);
    const int base = (logical & 3) * 8;            // dim group start
    const float4 cA = *(const float4*)(cb + k * DIM + base);
    const float4 cB = *(const float4*)(cb + k * DIM + base + 4);
    float v[8] = {cA.x, cA.y, cA.z, cA.w, cB.x, cB.y, cB.z, cB.w};

    half8 hv;
    if (logical < 4) {
#pragma unroll
      for (int i = 0; i < 8; ++i) hv[i] = (_Float16)v[i];
    } else {
#pragma unroll
      for (int i = 0; i < 8; ++i) hv[i] = (_Float16)(v[i] * v[i]);
    }
    *(half8*)(Bh + (size_t)k * 64 + s_phys * 8) = hv;   // 16-B store, coalesced

    // column-major copy for merge rescans: lanes logical<4 cover dims 0..31
    const int col = (k >> 10) * 16 + (k & 15);
    const int j = (k >> 4) & 63;
    if (logical < 4) {
      float* dst = cbP + ((size_t)col * 64 + j) * 32 + base;
      *(float4*)dst = cA;
      *(float4*)(dst + 4) = cB;
    }

    // per-k norms: lanes with logical<4 cover dims 0..31 exactly once
    float s2 = 0.0f, s4 = 0.0f;
    if (logical < 4) {
#pragma unroll
      for (int i = 0; i < 8; ++i) {
        const float c2 = v[i] * v[i];
        s2 += c2;
        s4 += c2 * c2;
      }
    }
#pragma unroll
    for (int mask = 1; mask <= 4; mask <<= 1) {     // 8-lane group reduce
      s2 += __shfl_xor(s2, mask);
      s4 += __shfl_xor(s4, mask);
    }
    if (s_phys == 0) {
      atomicMax((unsigned*)&CN1[col], __float_as_uint(sqrtf(s2)));
      atomicMax((unsigned*)&CN2[col], __float_as_uint(sqrtf(s4)));
    }
  } else {
    // ---- z half: 4 tokens per block (1 per wave), fully coalesced ----
    const int tok = (blockIdx.x - 512) * 4 + w;
    const float4 mu4 = ((const float4*)z)[(size_t)tok * 128 + l];        // mu
    const float4 lv4 = ((const float4*)z)[(size_t)tok * 128 + 64 + l];   // logvar
    const int d = l >> 1;
    const int c0 = (l & 1) * 4;
    double kacc = 0.0;
#pragma unroll
    for (int e = 0; e < 4; ++e) {
      const float mu = ((const float*)&mu4)[e];
      float lv = ((const float*)&lv4)[e];
      lv = fminf(fmaxf(lv, -30.0f), 20.0f);
      const float stdv = expf(0.5f * lv);
      const float iv = 1.0f / (stdv * stdv);   // identical to R2 expression
      const float p = mu * iv;
      const float q = 0.5f * (1.0f - iv);
      const size_t row = (size_t)tok * 8 + c0 + e;
      PQ[row * 64 + d] = p;                    // contiguous across lanes
      PQ[row * 64 + 32 + d] = q;
      Ah[row * 64 + d] = (_Float16)p;
      Ah[row * 64 + 32 + d] = (_Float16)q;
      kacc += (double)(mu * mu + stdv * stdv - 1.0f - lv);
    }
#pragma unroll
    for (int off = 32; off > 0; off >>= 1) kacc += __shfl_down(kacc, off);
    __shared__ double wsum[4];
    if (l == 0) wsum[w] = kacc;
    __syncthreads();
    if (threadIdx.x == 0)
      atomicAdd(klsum, (wsum[0] + wsum[1]) + (wsum[2] + wsum[3]));
  }
}

// async global->LDS, 16B per lane; dest must be linear in lane order.
__device__ __forceinline__ void gload_lds16(const _Float16* g, _Float16* l) {
  __builtin_amdgcn_global_load_lds(
      (__attribute__((address_space(1))) void*)(g),
      (__attribute__((address_space(3))) void*)(l), 16, 0, 0);
}

// grid (32, 16): x = rowgroup (512 rows), y = split. 4 waves x 128 rows each
// (8 rowtiles, A resident = 64 VGPR). B staged through 2 x 32 KB LDS buffers
// (16 tiles/chunk) via global_load_lds; 4 chunks, 1 barrier each. (R19/R22)
__global__ __launch_bounds__(256, 2) void filter_kernel(const _Float16* __restrict__ Ah,
                                                        const _Float16* __restrict__ Bh,
                                                        _Float16* __restrict__ W1) {
  __shared__ _Float16 sB[2][16384];   // 2 x 32 KB
  const int tid = threadIdx.x;
  const int lane = tid & 63;
  const int wave = tid >> 6;
  const int split = blockIdx.y;
  const int rowbase = blockIdx.x * 512 + wave * 128;   // 8 rowtiles of 16
  const int c16 = lane & 15, quad = lane >> 4;

  const _Float16* gB = Bh + (size_t)split * SPLITK * 64;  // 128 KB region

  // async-stage chunk 0 -> buf 0 (linear copy: Bh pre-swizzled in prep)
#pragma unroll
  for (int j = 0; j < 8; ++j)
    gload_lds16(gB + j * 2048 + tid * 8, &sB[0][j * 2048 + tid * 8]);

  half8 uh0[8], uh1[8];
#pragma unroll
  for (int rt = 0; rt < 8; ++rt) {
    const size_t abase = (size_t)(rowbase + rt * 16 + c16) * 64 + quad * 8;
    uh0[rt] = *(const half8*)(Ah + abase);
    uh1[rt] = *(const half8*)(Ah + abase + 32);
  }

  float a1[8][4];
#pragma unroll
  for (int rt = 0; rt < 8; ++rt)
#pragma unroll
    for (int r = 0; r < 4; ++r) a1[rt][r] = -INFINITY;

  const f32x4 fzero = {0.f, 0.f, 0.f, 0.f};
  // swizzled read offsets (halfs): row c16, physical slot = logical ^ (c16&7)
  const int key = c16 & 7;
  const int rs0h = c16 * 64 + (quad ^ key) * 8;         // p-part (slots 0-3)
  const int rs1h = c16 * 64 + ((quad + 4) ^ key) * 8;   // q-part (slots 4-7)

  __syncthreads();   // chunk 0 landed (compiler drains vmcnt before barrier)

#pragma unroll 1
  for (int ch = 0; ch < 4; ++ch) {
    if (ch < 3) {    // issue next chunk into the idle buffer (async)
      const _Float16* src = gB + (size_t)(ch + 1) * 16384;
      _Float16* dst = &sB[(ch + 1) & 1][0];
#pragma unroll
      for (int j = 0; j < 8; ++j)
        gload_lds16(src + j * 2048 + tid * 8, dst + j * 2048 + tid * 8);
    }
    const _Float16* buf = &sB[ch & 1][0];
#pragma unroll 1
    for (int tp = 0; tp < 8; ++tp) {          // 8 tile-pairs per chunk
      const _Float16* b0 = buf + (2 * tp) * 1024;
      const _Float16* b1 = b0 + 1024;
      const half8 x0 = *(const half8*)(b0 + rs0h);
      const half8 x1 = *(const half8*)(b0 + rs1h);
      const half8 y0 = *(const half8*)(b1 + rs0h);
      const half8 y1 = *(const half8*)(b1 + rs1h);
#pragma unroll
      for (int rt = 0; rt < 8; ++rt) {
        f32x4 h0 = __builtin_amdgcn_mfma_f32_16x16x32_f16(uh0[rt], x0, fzero, 0, 0, 0);
        h0 = __builtin_amdgcn_mfma_f32_16x16x32_f16(uh1[rt], x1, h0, 0, 0, 0);
        f32x4 h1 = __builtin_amdgcn_mfma_f32_16x16x32_f16(uh0[rt], y0, fzero, 0, 0, 0);
        h1 = __builtin_amdgcn_mfma_f32_16x16x32_f16(uh1[rt], y1, h1, 0, 0, 0);
#pragma unroll
        for (int r = 0; r < 4; ++r)
          a1[rt][r] = fmaxf(fmaxf(h0[r], h1[r]), a1[rt][r]);   // v_max3
      }
    }
    __syncthreads();  // all waves done with buf; next chunk landed (vmcnt 0)
  }

  // W1 fp16 [split][row][16]: block-exclusive contiguous 16KB, no RMW.
#pragma unroll
  for (int rt = 0; rt < 8; ++rt)
#pragma unroll
    for (int r = 0; r < 4; ++r) {
      const int row_r = rowbase + rt * 16 + quad * 4 + r;   // C: row=quad*4+r
      W1[((size_t)split * NROWS + row_r) * 16 + c16] =
          (_Float16)fmaxf(a1[rt][r], -65504.0f);
    }
}

// exact fp32 score from the COLUMN-MAJOR copy: column col, slot j (=lane).
// 8 KB contiguous per column scan; identical float expression to R2.
__device__ __forceinline__ float exact_score_cm(const float4* __restrict__ cbP4,
                                                const float4* __restrict__ spq,
                                                int col, int j) {
  const float4* cp = cbP4 + ((size_t)col * 64 + j) * 8;
  float s0 = 0.0f, s1 = 0.0f, s2 = 0.0f, s3 = 0.0f;
#pragma unroll
  for (int m = 0; m < 8; ++m) {
    const float4 cv = cp[m];
    const float4 pv = spq[m];        // p[4m..4m+3]
    const float4 qv = spq[8 + m];    // q[4m..4m+3]
    s0 = fmaf(cv.x, fmaf(qv.x, cv.x, pv.x), s0);
    s1 = fmaf(cv.y, fmaf(qv.y, cv.y, pv.y), s1);
    s2 = fmaf(cv.z, fmaf(qv.z, cv.z, pv.z), s2);
    s3 = fmaf(cv.w, fmaf(qv.w, cv.w, pv.w), s3);
  }
  return (s0 + s1) + (s2 + s3);
}

// 1 wave per row; 4 rows per block (R22 structure). Seed E* by fully
// rescanning the argmax column, then full rescan of every column with
// w + Btot_col >= E*. Phase-B loop FULLY UNROLLED (R26 fix): w[i]/bt[i]
// accesses are compile-time-static -> registers, zero scratch.
__global__ __launch_bounds__(256, 4) void merge_kernel(const float* __restrict__ PQ,
                                                       const float* __restrict__ cb,
                                                       const float* __restrict__ cbP,
                                                       const _Float16* __restrict__ W1,
                                                       const float* __restrict__ CN1,
                                                       const float* __restrict__ CN2,
                                                       const double* __restrict__ klsum,
                                                       float* __restrict__ out0,
                                                       float* __restrict__ out1,
                                                       float* __restrict__ out2) {
  __shared__ float4 spq_s[4][16];
  const int lane = threadIdx.x & 63;
  const int wave = threadIdx.x >> 6;
  const int row = blockIdx.x * 4 + wave;

  if (lane < 16)
    spq_s[wave][lane] = ((const float4*)(PQ + (size_t)row * 64))[lane];
  __syncthreads();
  const float4* spq = spq_s[wave];
  const float4* __restrict__ cbP4 = (const float4*)cbP;

  // per-row norms ||p||2, ||q||2
  float sp = 0.0f, sq = 0.0f;
  if (lane < DIM) {
    const float pd = ((const float*)spq)[lane];
    const float qd = ((const float*)spq)[32 + lane];
    sp = pd * pd;
    sq = qd * qd;
  }
#pragma unroll
  for (int off = 1; off < 32; off <<= 1) {
    sp += __shfl_xor(sp, off);
    sq += __shfl_xor(sq, off);
  }
  const float pn = sqrtf(__shfl(sp, 0));
  const float qn = sqrtf(__shfl(sq, 0));

  // load 256 column maxima (fp16, layout [split][row][16]); col = i*64 + lane
  float w[4];
#pragma unroll
  for (int i = 0; i < 4; ++i)
    w[i] = (float)W1[((size_t)(i * 4 + (lane >> 4)) * NROWS + row) * 16 + (lane & 15)];
  float As = fmaxf(fmaxf(w[0], w[1]), fmaxf(w[2], w[3]));
#pragma unroll
  for (int off = 1; off < 64; off <<= 1) As = fmaxf(As, __shfl_xor(As, off));
  const float slack = 2e-5f * (fabsf(As) + 1.0f) + 1e-3f;

  // per-column rigorous bounds + fp16-rounding term
  float bt[4];
#pragma unroll
  for (int i = 0; i < 4; ++i) {
    const int col = i * 64 + lane;
    bt[i] = 1.05e-3f * (pn * CN1[col] + qn * CN2[col]) + slack
            + 5e-4f * fabsf(w[i]);
  }

  // ---- seed: full exact rescan of (one) column achieving As ----
  int done_col = -1;
#pragma unroll
  for (int i = 0; i < 4; ++i) {
    if (done_col < 0) {
      const unsigned long long m = __ballot(w[i] == As);
      if (m) done_col = i * 64 + __builtin_ctzll(m);
    }
  }
  // orig k for column slot j=lane (tie-break identity preserved)
  const int k0 = (done_col >> 4) * SPLITK + lane * 16 + (done_col & 15);
  float best = exact_score_cm(cbP4, spq, done_col, lane);
  int bk = k0;
#pragma unroll
  for (int off = 1; off < 64; off <<= 1) {
    const float ov = __shfl_xor(best, off);
    const int ok = __shfl_xor(bk, off);
    if (ov > best || (ov == best && ok < bk)) { best = ov; bk = ok; }
  }
  const float Estar = best;   // exact score of a real k; all lanes agree

  // ---- full rescan of every other column that could still hold the max ----
  // FULLY UNROLLED (R26): i is compile-time-constant in every w[i]/bt[i].
#pragma unroll
  for (int i = 0; i < 4; ++i) {
    unsigned long long m = __ballot(w[i] + bt[i] >= Estar);
    if ((done_col >> 6) == i) m &= ~(1ull << (done_col & 63));
    while (m) {
      const int e = __builtin_ctzll(m);
      m &= m - 1;
      const int col = i * 64 + e;
      const int k = (col >> 4) * SPLITK + lane * 16 + (col & 15);
      const float sc = exact_score_cm(cbP4, spq, col, lane);
      if (sc > best || (sc == best && k < bk)) { best = sc; bk = k; }
    }
  }
  // final cross-lane argmax, min-k on ties (numpy first-max)
#pragma unroll
  for (int off = 1; off < 64; off <<= 1) {
    const float ov = __shfl_xor(best, off);
    const int ok = __shfl_xor(bk, off);
    if (ov > best || (ov == best && ok < bk)) { best = ov; bk = ok; }
  }
  if (lane == 0) out2[row] = (float)bk;
  const int tt = row >> 3, cc = row & 7;
  if (lane < DIM) out0[tt * 256 + lane * 8 + cc] = cb[bk * DIM + lane];
  if (blockIdx.x == 0 && threadIdx.x == 0)
    out1[0] = (float)(klsum[0] * (1.4426 * 0.5) / (double)NROWS);
}

extern "C" void kernel_launch(void* const* d_in, const int* in_sizes, int n_in,
                              void* d_out, int out_size, void* d_ws, size_t ws_size,
                              hipStream_t stream) {
  const float* z  = (const float*)d_in[0];
  const float* cb = (const float*)d_in[2];   // d_in[1]=noise unused (STE cancels)

  char* ws = (char*)d_ws;
  double* klsum  = (double*)(ws + WS_KL);
  float*     CN1 = (float*)(ws + WS_CN1);
  float*     CN2 = (float*)(ws + WS_CN2);
  float*      PQ = (float*)(ws + WS_PQ);
  _Float16*   Ah = (_Float16*)(ws + WS_AH);
  _Float16*   Bh = (_Float16*)(ws + WS_BH);
  _Float16*   W1 = (_Float16*)(ws + WS_W1);
  float*     cbP = (float*)(ws + WS_CBP);

  float* out0 = (float*)d_out;            // 524288
  float* out1 = out0 + 524288;            // 1
  float* out2 = out1 + 1;                 // 16384

  (void)hipMemsetAsync(ws, 0, 4096, stream);   // klsum, CN1, CN2 = 0
  prep_kernel<<<1024, 256, 0, stream>>>(cb, z, Bh, cbP, CN1, CN2, PQ, Ah, klsum);
  dim3 fgrid(32, NSPLIT);
  filter_kernel<<<fgrid, 256, 0, stream>>>(Ah, Bh, W1);
  merge_kernel<<<NROWS / 4, 256, 0, stream>>>(PQ, cb, cbP, W1, CN1, CN2, klsum,
                                              out0, out1, out2);
}